// Round 8
// baseline (7383.346 us; speedup 1.0000x reference)
//
#include <hip/hip_runtime.h>
#include <math.h>

#define NOT_FIREDf 9999.0f
typedef float f32x2 __attribute__((ext_vector_type(2)));

// packed f32x2 add (bit-exact element-wise IEEE add, 1 inst for 2 adds)
#define PKADD(ACC, W) asm("v_pk_add_f32 %0, %0, %1" : "+v"(ACC) : "v"(W))
// compiler-only memory fence (orders LDS ops in program order; HW is in-order per wave)
#define CFENCE() asm volatile("" ::: "memory")

// Zero-padded conv2 weights in d_ws:
// w2p[((ci*5 + dy)*19 + rx)*64 + co] = (rx-7 in [0,5)) ? w2[(co*12+ci)*25 + dy*5 + (rx-7)] : 0
__global__ void w2_pad_kernel(const float* __restrict__ w2, float* __restrict__ w2p) {
    int idx = blockIdx.x * 256 + threadIdx.x;
    if (idx >= 72960) return;
    int co = idx & 63;
    int r = idx >> 6;            // ci*95 + dy*19 + rx
    int rx = r % 19;
    int q = r / 19;
    int dy = q % 5;
    int ci = q / 5;
    int dx = rx - 7;
    w2p[idx] = ((unsigned)dx < 5u) ? w2[(co * 12 + ci) * 25 + dy * 5 + dx] : 0.0f;
}

template <int USE_T>
__global__ void __launch_bounds__(256, 2)
snn_wave_kernel(const float* __restrict__ img,
                const float* __restrict__ w1g,
                const float* __restrict__ b1g,
                const float* __restrict__ b2g,
                const float* __restrict__ w2raw,
                const float* __restrict__ w2p,
                const float* __restrict__ fcw,
                const float* __restrict__ b3g,
                float* __restrict__ out,
                const int B) {
    const int tid  = threadIdx.x;
    const int lane = tid & 63;
    const int wv   = tid >> 6;               // 4 waves = 4 independent images
    const int bimg = blockIdx.x * 4 + wv;

    __shared__ __align__(16) float w1s[300]; // transposed [k=ky*5+kx][c], block-shared
    __shared__ __align__(8)  float b1s[12];
    __shared__ float th_lds[80];
    __shared__ unsigned char  stin[4][784];
    __shared__ unsigned short evlist[4][784];   // t-sorted input events (py<<8|px)
    __shared__ unsigned short off[4][81];
    __shared__ int            hist[4][80];
    __shared__ unsigned short ev1[4][1728];     // this-step pooled-l1 events (c<<8|py<<4|px)
    __shared__ int            cnt1[4];
    __shared__ unsigned int   pm1[4][54];
    __shared__ unsigned int   pm2[4][32];
    __shared__ unsigned int   e2list[4][1024];  // (t<<16)|nhwc_flat
    __shared__ int            e2cnt[4];

    // ---- block-shared init ----
    for (int i = tid; i < 300; i += 256) {
        int k = i / 12, c = i - k * 12;
        w1s[i] = w1g[c * 25 + k];
    }
    if (tid < 12) b1s[tid] = b1g[tid];
    if (tid < 80) {
        float xa = (0.0f - (float)tid) / 20.0f;
        th_lds[tid] = (float)exp((double)xa);           // correctly-rounded f32 exp
    }

    // ---- per-wave init (no cross-wave deps) ----
    const bool act = (bimg < B);
    if (act) {
        for (int i = lane; i < 80; i += 64) hist[wv][i] = 0;
        if (lane < 54) pm1[wv][lane] = 0u;
        if (lane < 32) pm2[wv][lane] = 0u;
        if (lane == 0) { cnt1[wv] = 0; e2cnt[wv] = 0; }
        CFENCE();
        for (int i = lane; i < 784; i += 64) {
            float p = img[bimg * 784 + i];
            p = fmaxf(p, 1e-5f);
            float lg = (float)log((double)p);           // correctly-rounded f32 log
            float s = ceilf(fmaxf(-17.452274f * lg, 0.0f));
            int si = (int)fminf(s, 255.0f);
            stin[wv][i] = (unsigned char)si;
            if (si < 80) atomicAdd(&hist[wv][si], 1);
        }
        CFENCE();
        if (lane == 0) {
            int acc = 0;
            for (int t = 0; t < 80; ++t) { off[wv][t] = (unsigned short)acc; acc += hist[wv][t]; }
            off[wv][80] = (unsigned short)acc;
        }
        CFENCE();
        {   // evlist fill: lane owns bins `lane` and `64+lane` (lane<16); pixel-order per bin
            int k0 = off[wv][lane];
            int k1 = (lane < 16) ? off[wv][64 + lane] : 0;
            int py = 0, px = 0;
            for (int i = 0; i < 784; ++i) {
                const int tt = stin[wv][i];             // broadcast read
                const unsigned pk = (unsigned)((py << 8) | px);
                if (tt == lane) evlist[wv][k0++] = (unsigned short)pk;
                if ((lane < 16) & (tt == 64 + lane)) evlist[wv][k1++] = (unsigned short)pk;
                if (++px == 28) { px = 0; ++py; }
            }
        }
        CFENCE();
    }
    __syncthreads();     // the ONLY block barrier (w1s/b1s/th ready)
    if (!act) return;

    // ---- register state ----
    // lane owns a 3x3 pixel block of the 24x24 conv1 plane: y0=(lane>>3)*3, x0=(lane&7)*3
    const int y0 = (lane >> 3) * 3;
    const int x0 = (lane & 7) * 3;
    f32x2 v1r[9][6];                          // [gy*3+gx][ch-pair]
#pragma unroll
    for (int g = 0; g < 9; ++g)
#pragma unroll
        for (int j = 0; j < 6; ++j) v1r[g][j] = (f32x2){0.0f, 0.0f};
    f32x2 acc2[32];                           // v2: pos (OY, ox) -> acc2[OY*4+(ox>>1)], co=lane
#pragma unroll
    for (int j = 0; j < 32; ++j) acc2[j] = (f32x2){0.0f, 0.0f};
    const float b2v = b2g[lane];
    const f32x2 b2p = (f32x2){b2v, b2v};

    // ---- time loop: NO barriers ----
    for (int t = 0; t < 80; ++t) {
        const float th = th_lds[t];

        // phase 1: input events -> v1 regs
        {
            const int e0 = off[wv][t], e1 = off[wv][t + 1];
            for (int e = e0; e < e1; ++e) {
                const unsigned pk = evlist[wv][e];      // broadcast
                const int ry = (int)(pk >> 8) - y0;
                const int rx = (int)(pk & 255u) - x0;
#pragma unroll
                for (int gy = 0; gy < 3; ++gy) {
                    const int dy = ry - gy;
                    if ((unsigned)dy < 5u) {
#pragma unroll
                        for (int gx = 0; gx < 3; ++gx) {
                            const int dx = rx - gx;
                            if ((unsigned)dx < 5u) {
                                const f32x2* wp = (const f32x2*)&w1s[(dy * 5 + dx) * 12];
                                f32x2 a0 = wp[0], a1 = wp[1], a2 = wp[2];
                                f32x2 a3 = wp[3], a4 = wp[4], a5 = wp[5];
                                PKADD(v1r[gy * 3 + gx][0], a0);
                                PKADD(v1r[gy * 3 + gx][1], a1);
                                PKADD(v1r[gy * 3 + gx][2], a2);
                                PKADD(v1r[gy * 3 + gx][3], a3);
                                PKADD(v1r[gy * 3 + gx][4], a4);
                                PKADD(v1r[gy * 3 + gx][5], a5);
                            }
                        }
                    }
                }
            }
        }
        // layer1 check: stepwise bias + per-group max screen + exact pass on crossing
        {
            const f32x2* bp = (const f32x2*)b1s;
            const f32x2 c0 = bp[0], c1 = bp[1], c2 = bp[2];
            const f32x2 c3 = bp[3], c4 = bp[4], c5 = bp[5];
#pragma unroll
            for (int g = 0; g < 9; ++g) {
                PKADD(v1r[g][0], c0); PKADD(v1r[g][1], c1); PKADD(v1r[g][2], c2);
                PKADD(v1r[g][3], c3); PKADD(v1r[g][4], c4); PKADD(v1r[g][5], c5);
                float m = fmaxf(fmaxf(fmaxf(v1r[g][0].x, v1r[g][0].y),
                                      fmaxf(v1r[g][1].x, v1r[g][1].y)),
                                fmaxf(fmaxf(v1r[g][2].x, v1r[g][2].y),
                                      fmaxf(v1r[g][3].x, v1r[g][3].y)));
                m = fmaxf(m, fmaxf(fmaxf(v1r[g][4].x, v1r[g][4].y),
                                   fmaxf(v1r[g][5].x, v1r[g][5].y)));
                if (m >= th) {
                    const int Y = y0 + g / 3, X = x0 + g % 3;      // g/3,g%3 compile-time
                    const int pyp = Y >> 1, pxp = X >> 1;
#pragma unroll
                    for (int j = 0; j < 6; ++j) {
                        if (v1r[g][j].x >= th) {
                            v1r[g][j].x = -__builtin_inff();
                            const int p = (j * 2) * 144 + pyp * 12 + pxp;
                            const unsigned bit = 1u << (p & 31);
                            const unsigned old = atomicOr(&pm1[wv][p >> 5], bit);
                            if (!(old & bit)) {
                                const int pos = atomicAdd(&cnt1[wv], 1);
                                ev1[wv][pos] = (unsigned short)(((j * 2) << 8) | (pyp << 4) | pxp);
                            }
                        }
                        if (v1r[g][j].y >= th) {
                            v1r[g][j].y = -__builtin_inff();
                            const int p = (j * 2 + 1) * 144 + pyp * 12 + pxp;
                            const unsigned bit = 1u << (p & 31);
                            const unsigned old = atomicOr(&pm1[wv][p >> 5], bit);
                            if (!(old & bit)) {
                                const int pos = atomicAdd(&cnt1[wv], 1);
                                ev1[wv][pos] = (unsigned short)(((j * 2 + 1) << 8) | (pyp << 4) | pxp);
                            }
                        }
                    }
                }
            }
        }
        CFENCE();

        // phase 2: pooled-l1 events -> v2 (scalar decode, all 8 rows in this wave)
        {
            const int ne1 = cnt1[wv];
            for (int e = 0; e < ne1; ++e) {
                const int pks = __builtin_amdgcn_readfirstlane((int)ev1[wv][e]);
                const int ci = pks >> 8;
                const int py = (pks >> 4) & 15;
                const int px = pks & 15;
                if (USE_T) {
                    const float* qb = w2p + (px + 7) * 64 + lane;
#pragma unroll
                    for (int OY = 0; OY < 8; ++OY) {
                        const int dy = py - OY;                    // scalar
                        if ((unsigned)dy < 5u) {                   // scalar branch
                            const float* q = qb + (ci * 5 + dy) * 1216;
#pragma unroll
                            for (int i = 0; i < 4; ++i) {
                                f32x2 w;
                                w.x = q[-((2 * i) * 64)];
                                w.y = q[-((2 * i + 1) * 64)];
                                PKADD(acc2[OY * 4 + i], w);
                            }
                        }
                    }
                } else {
                    const float* cb = w2raw + (lane * 12 + ci) * 25;
#pragma unroll
                    for (int OY = 0; OY < 8; ++OY) {
                        const int dy = py - OY;
                        if ((unsigned)dy < 5u) {
                            const float* r = cb + dy * 5;
#pragma unroll
                            for (int i = 0; i < 4; ++i) {
                                const int dxa = px - 2 * i;
                                const int dxb = dxa - 1;
                                const int dxac = dxa < 0 ? 0 : (dxa > 4 ? 4 : dxa);
                                const int dxbc = dxb < 0 ? 0 : (dxb > 4 ? 4 : dxb);
                                acc2[OY * 4 + i].x = fmaf(r[dxac],
                                    ((unsigned)dxa < 5u) ? 1.0f : 0.0f, acc2[OY * 4 + i].x);
                                acc2[OY * 4 + i].y = fmaf(r[dxbc],
                                    ((unsigned)dxb < 5u) ? 1.0f : 0.0f, acc2[OY * 4 + i].y);
                            }
                        }
                    }
                }
            }
            CFENCE();
            if (lane == 0) cnt1[wv] = 0;
            CFENCE();
        }

        // layer2 check: stepwise bias + per-row max screen + exact pass
        {
#pragma unroll
            for (int OY = 0; OY < 8; ++OY) {
                PKADD(acc2[OY * 4 + 0], b2p); PKADD(acc2[OY * 4 + 1], b2p);
                PKADD(acc2[OY * 4 + 2], b2p); PKADD(acc2[OY * 4 + 3], b2p);
                float m = fmaxf(fmaxf(fmaxf(acc2[OY * 4 + 0].x, acc2[OY * 4 + 0].y),
                                      fmaxf(acc2[OY * 4 + 1].x, acc2[OY * 4 + 1].y)),
                                fmaxf(fmaxf(acc2[OY * 4 + 2].x, acc2[OY * 4 + 2].y),
                                      fmaxf(acc2[OY * 4 + 3].x, acc2[OY * 4 + 3].y)));
                if (m >= th) {
#pragma unroll
                    for (int i = 0; i < 4; ++i) {
                        if (acc2[OY * 4 + i].x >= th) {
                            acc2[OY * 4 + i].x = -__builtin_inff();
                            const int p2 = ((OY >> 1) * 4 + ((2 * i) >> 1)) * 64 + lane;
                            const unsigned bit = 1u << (p2 & 31);
                            const unsigned old = atomicOr(&pm2[wv][p2 >> 5], bit);
                            if (!(old & bit)) {
                                const int pos = atomicAdd(&e2cnt[wv], 1);
                                e2list[wv][pos] = ((unsigned)t << 16) | (unsigned)p2;
                            }
                        }
                        if (acc2[OY * 4 + i].y >= th) {
                            acc2[OY * 4 + i].y = -__builtin_inff();
                            const int p2 = ((OY >> 1) * 4 + ((2 * i + 1) >> 1)) * 64 + lane;
                            const unsigned bit = 1u << (p2 & 31);
                            const unsigned old = atomicOr(&pm2[wv][p2 >> 5], bit);
                            if (!(old & bit)) {
                                const int pos = atomicAdd(&e2cnt[wv], 1);
                                e2list[wv][pos] = ((unsigned)t << 16) | (unsigned)p2;
                            }
                        }
                    }
                }
            }
        }
        CFENCE();
    }

    // ---- output layer: replay t-sorted layer2 event log (no feedback) ----
    if (lane < 10) {
        const int n2 = e2cnt[wv];
        const float b3v = b3g[lane];
        float v = 0.0f;
        float ot = NOT_FIREDf;
        int ptr = 0;
        for (int t = 0; t < 80; ++t) {
            float acc = 0.0f;
            while (ptr < n2 && (int)(e2list[wv][ptr] >> 16) == t) {
                acc += fcw[(e2list[wv][ptr] & 0xFFFFu) * 10 + lane];
                ++ptr;
            }
            v += acc + b3v;
            if (ot == NOT_FIREDf && v >= th_lds[t]) ot = (float)t;
        }
        out[bimg * 10 + lane] = ot;
    }
}

extern "C" void kernel_launch(void* const* d_in, const int* in_sizes, int n_in,
                              void* d_out, int out_size, void* d_ws, size_t ws_size,
                              hipStream_t stream) {
    const float* img = (const float*)d_in[0];
    const float* w1  = (const float*)d_in[1];
    const float* b1  = (const float*)d_in[2];
    const float* w2  = (const float*)d_in[3];
    const float* b2  = (const float*)d_in[4];
    const float* fcw = (const float*)d_in[5];
    const float* b3  = (const float*)d_in[6];
    float* out = (float*)d_out;

    const int B = in_sizes[0] / (28 * 28);
    const int nblk = (B + 3) / 4;

    float* w2p = (float*)d_ws;
    const int use_t = (ws_size >= 72960u * sizeof(float)) ? 1 : 0;
    if (use_t) {
        hipLaunchKernelGGL(w2_pad_kernel, dim3(285), dim3(256), 0, stream, w2, w2p);
        hipLaunchKernelGGL(snn_wave_kernel<1>, dim3(nblk), dim3(256), 0, stream,
                           img, w1, b1, b2, w2, w2p, fcw, b3, out, B);
    } else {
        hipLaunchKernelGGL(snn_wave_kernel<0>, dim3(nblk), dim3(256), 0, stream,
                           img, w1, b1, b2, w2, w2p, fcw, b3, out, B);
    }
}